// Round 4
// baseline (667.076 us; speedup 1.0000x reference)
//
#include <hip/hip_runtime.h>
#include <cstdint>

#define S_LEN 2048
#define B_SZ 8
#define D_DIM 2048
#define M_DIM (S_LEN * B_SZ)   // 16384 tokens
#define CHAINS (B_SZ * D_DIM)  // 16384 scan chains
#define BK 64
#define KTILES (D_DIM / BK)    // 32

typedef __bf16 bf16;
typedef bf16 bf16x8 __attribute__((ext_vector_type(8)));
typedef bf16 bf16x4 __attribute__((ext_vector_type(4)));
typedef float f32x4 __attribute__((ext_vector_type(4)));

// ---------------- async global->LDS (16B, wave-uniform LDS base + lane*16) ----
__device__ __forceinline__ void async_copy16(void* lds, const void* g) {
    __builtin_amdgcn_global_load_lds(
        (const __attribute__((address_space(1))) unsigned int*)g,
        (__attribute__((address_space(3))) unsigned int*)lds,
        16, 0, 0);
}

// ---------------- fp32 -> bf16 conversion of x, W_x, W_a ---------------------
__global__ void k_convert(const float4* __restrict__ x,
                          const float4* __restrict__ wx,
                          const float4* __restrict__ wa,
                          bf16* __restrict__ xb,
                          bf16* __restrict__ wxb,
                          bf16* __restrict__ wab) {
    const long NX4 = (long)M_DIM * D_DIM / 4;   // 8388608
    const long NW4 = (long)D_DIM * D_DIM / 4;   // 1048576
    const long total = NX4 + 2 * NW4;
    for (long i = (long)blockIdx.x * blockDim.x + threadIdx.x; i < total;
         i += (long)gridDim.x * blockDim.x) {
        const float4* s; bf16* d; long k;
        if (i < NX4)            { s = x;  d = xb;  k = i; }
        else if (i < NX4 + NW4) { s = wx; d = wxb; k = i - NX4; }
        else                    { s = wa; d = wab; k = i - NX4 - NW4; }
        float4 v = s[k];
        bf16x4 o;
        o[0] = (bf16)v.x; o[1] = (bf16)v.y; o[2] = (bf16)v.z; o[3] = (bf16)v.w;
        *reinterpret_cast<bf16x4*>(d + 4 * k) = o;
    }
}

// ---------------- cvec[e] = -C * softplus(a_param[e]) ------------------------
__global__ void k_cvec(const float* __restrict__ ap, float* __restrict__ cv) {
    int e = blockIdx.x * blockDim.x + threadIdx.x;
    if (e < D_DIM) {
        float v = ap[e];
        cv[e] = -8.0f * log1pf(expf(v));
    }
}

// ---------------- fused dual-GEMM, gate-split waves, m97-style loop ----------
// Tile: BM=128 tokens x BN=64 channels x BK=64, 4 waves.
// wave w: gate = w>>1 (0=x,1=a), wm = w&1; per-wave output 64x64 of ONE gate
// => acc = 16 x f32x4 = 64 AGPR (half of dual-gate design) -> 3 blocks/CU.
// LDS: A 128x64 bf16 (16KB) | Bx 64x64 (8KB) | Ba 64x64 (8KB) = 32KB staging;
// epilogue reuses it as za exchange buffer [2][64][66] f32 (33792 B).
__global__ __launch_bounds__(256, 3) void k_gemm(
    const bf16* __restrict__ xb,    // [M][D] bf16
    const bf16* __restrict__ wxb,   // [D][D] bf16 (row e, col d)
    const bf16* __restrict__ wab,   // [D][D] bf16
    const float* __restrict__ x32,  // original x fp32
    const float* __restrict__ bx,
    const float* __restrict__ ba,
    const float* __restrict__ cv,
    float* __restrict__ abuf,       // [M][D] fp32
    float* __restrict__ y)          // [M][D] fp32 (normed_x staged here)
{
    __shared__ __align__(16) char smem[34816];

    const int tid  = threadIdx.x;
    const int lane = tid & 63;
    const int w    = tid >> 6;       // 0..3
    const int gate = w >> 1;         // 0 = x, 1 = a
    const int wm   = w & 1;          // 64-row half of the A tile

    // XCD-bijective swizzle (4096 wgs = 8 x 512); within an XCD chunk,
    // consecutive wgids share the same W N-panel (B hot in L2, A streams).
    const int orig = blockIdx.x;
    const int wgid = (orig & 7) * 512 + (orig >> 3);
    const int m0 = (wgid & 127) * 128;   // 128 M-blocks
    const int e0 = (wgid >> 7) * 64;     // 32 N-blocks

    char* sA  = smem;            // 128 rows x 128B
    char* sBx = smem + 16384;    // 64 rows x 128B
    char* sBa = smem + 24576;    // 64 rows x 128B
    char* sB  = gate ? sBa : sBx;

    // staging geometry: one instr = 1KB = 8 rows of 128B
    const int srow  = lane >> 3;                 // 0..7
    const int swz16 = ((lane & 7) ^ srow) * 16;  // inverse-swizzled src chunk

    const char* gA  = (const char*)xb;
    const char* gBx = (const char*)wxb;
    const char* gBa = (const char*)wab;

    f32x4 acc[4][4];
#pragma unroll
    for (int i = 0; i < 4; ++i)
#pragma unroll
        for (int j = 0; j < 4; ++j) acc[i][j] = (f32x4)(0.0f);

    const int rL = lane & 15;

    for (int kt = 0; kt < KTILES; ++kt) {
        const long kb = (long)kt * 128 + swz16;

        // ---- stage tile (per wave: 4 A + 2 Bx + 2 Ba = 8 x 1KB) ----
#pragma unroll
        for (int jj = 0; jj < 4; ++jj) {
            const int br = w * 32 + jj * 8;
            async_copy16(sA + br * 128, gA + ((long)(m0 + br + srow) * 4096 + kb));
        }
#pragma unroll
        for (int jj = 0; jj < 2; ++jj) {
            const int br = w * 16 + jj * 8;
            async_copy16(sBx + br * 128, gBx + ((long)(e0 + br + srow) * 4096 + kb));
            async_copy16(sBa + br * 128, gBa + ((long)(e0 + br + srow) * 4096 + kb));
        }
        __syncthreads();   // compiler emits vmcnt(0) drain before s_barrier

        // ---- compute: 2 k-steps of 16x16x32, 4x4 frags, one gate ----
#pragma unroll
        for (int ks = 0; ks < 2; ++ks) {
            const int ch = ((ks * 4 + (lane >> 4)) ^ (lane & 7)) * 16;
            bf16x8 af[4], bf[4];
#pragma unroll
            for (int i = 0; i < 4; ++i) {
                const int r = wm * 64 + i * 16 + rL;
                af[i] = *reinterpret_cast<const bf16x8*>(sA + r * 128 + ch);
            }
#pragma unroll
            for (int j = 0; j < 4; ++j) {
                const int r = j * 16 + rL;
                bf[j] = *reinterpret_cast<const bf16x8*>(sB + r * 128 + ch);
            }
#pragma unroll
            for (int i = 0; i < 4; ++i)
#pragma unroll
                for (int j = 0; j < 4; ++j)
                    acc[i][j] = __builtin_amdgcn_mfma_f32_16x16x32_bf16(
                        af[i], bf[j], acc[i][j], 0, 0, 0);
        }
        __syncthreads();  // protect LDS before next iteration's staging
    }

    // ---- epilogue: a-waves dump za to LDS, x-waves combine + store ----
    float* zl = (float*)smem;            // [2][64][66] f32, padded stride
    const int rgrp = lane >> 4;

    if (gate == 1) {
#pragma unroll
        for (int j = 0; j < 4; ++j)
#pragma unroll
            for (int i = 0; i < 4; ++i)
#pragma unroll
                for (int r = 0; r < 4; ++r) {
                    const int ml = i * 16 + rgrp * 4 + r;
                    const int el = j * 16 + rL;
                    zl[(wm * 64 + ml) * 66 + el] = acc[i][j][r];
                }
    }
    __syncthreads();
    if (gate == 0) {
#pragma unroll
        for (int j = 0; j < 4; ++j) {
            const int e = e0 + j * 16 + rL;
            const float bxv = bx[e];
            const float bav = ba[e];
            const float cvv = cv[e];
#pragma unroll
            for (int i = 0; i < 4; ++i) {
#pragma unroll
                for (int r = 0; r < 4; ++r) {
                    const int ml = i * 16 + rgrp * 4 + r;
                    const int m = m0 + wm * 64 + ml;
                    const float zx = acc[i][j][r] + bxv;
                    const float za = zl[(wm * 64 + ml) * 66 + j * 16 + rL] + bav;
                    const float gx = 1.0f / (1.0f + __expf(-zx));
                    const float ga = 1.0f / (1.0f + __expf(-za));
                    const float la = cvv * ga;
                    float a = __expf(la);
                    float mult = sqrtf(fmaxf(1.0f - a * a, 0.0f));
                    if (m < B_SZ) { a = 0.0f; mult = 1.0f; }  // s == 0 reset
                    const long o = (long)m * D_DIM + e;
                    const float xv = x32[o];
                    abuf[o] = a;
                    y[o] = xv * gx * mult;
                }
            }
        }
    }
}

// ---------------- in-place scan over S: h = a*h + xn, y <- h -----------------
__global__ __launch_bounds__(64) void k_scan(
    const float* __restrict__ abuf,
    float* __restrict__ y,           // contains xn; overwritten with h states
    const float* __restrict__ h0,
    float* __restrict__ hn) {
    const int c = blockIdx.x * 64 + threadIdx.x;  // chain id, 0..16383
    float h = h0[c];

    float av0[16], xv0[16], av1[16], xv1[16];
    // prologue: load group 0
#pragma unroll
    for (int j = 0; j < 16; ++j) {
        const long o = (long)j * CHAINS + c;
        av0[j] = abuf[o];
        xv0[j] = y[o];
    }
    // 128 groups of 16 steps, ping-pong double-buffer (static indexing only)
    for (int g = 0; g < 128; g += 2) {
        const long base1 = ((long)(g + 1) * 16) * CHAINS + c;
        if (g + 1 < 128) {
#pragma unroll
            for (int j = 0; j < 16; ++j) {
                av1[j] = abuf[base1 + (long)j * CHAINS];
                xv1[j] = y[base1 + (long)j * CHAINS];
            }
        }
        const long base0 = ((long)g * 16) * CHAINS + c;
#pragma unroll
        for (int j = 0; j < 16; ++j) {
            h = fmaf(av0[j], h, xv0[j]);
            y[base0 + (long)j * CHAINS] = h;
        }
        const long base2 = ((long)(g + 2) * 16) * CHAINS + c;
        if (g + 2 < 128) {
#pragma unroll
            for (int j = 0; j < 16; ++j) {
                av0[j] = abuf[base2 + (long)j * CHAINS];
                xv0[j] = y[base2 + (long)j * CHAINS];
            }
        }
        if (g + 1 < 128) {
#pragma unroll
            for (int j = 0; j < 16; ++j) {
                h = fmaf(av1[j], h, xv1[j]);
                y[base1 + (long)j * CHAINS] = h;
            }
        }
    }
    hn[c] = h;
}

// ---------------- launch -----------------------------------------------------
extern "C" void kernel_launch(void* const* d_in, const int* in_sizes, int n_in,
                              void* d_out, int out_size, void* d_ws, size_t ws_size,
                              hipStream_t stream) {
    const float* x  = (const float*)d_in[0];
    const float* h0 = (const float*)d_in[1];
    const float* Wx = (const float*)d_in[2];
    const float* bx = (const float*)d_in[3];
    const float* Wa = (const float*)d_in[4];
    const float* ba = (const float*)d_in[5];
    const float* ap = (const float*)d_in[6];
    float* out = (float*)d_out;

    char* ws = (char*)d_ws;
    bf16*  xb   = (bf16*)(ws);
    bf16*  wxb  = (bf16*)(ws + 67108864L);
    bf16*  wab  = (bf16*)(ws + 75497472L);
    float* cv   = (float*)(ws + 83886080L);
    float* abuf = (float*)(ws + 83894272L);

    float* y  = out;                         // S*B*D
    float* hn = out + (long)M_DIM * D_DIM;   // B*D

    k_convert<<<dim3(2048), dim3(256), 0, stream>>>(
        (const float4*)x, (const float4*)Wx, (const float4*)Wa, xb, wxb, wab);
    k_cvec<<<dim3(8), dim3(256), 0, stream>>>(ap, cv);
    k_gemm<<<dim3((M_DIM / 128) * (D_DIM / 64)), dim3(256), 0, stream>>>(
        xb, wxb, wab, x, bx, ba, cv, abuf, y);
    k_scan<<<dim3(CHAINS / 64), dim3(64), 0, stream>>>(abuf, y, h0, hn);
}

// Round 5
// 488.321 us; speedup vs baseline: 1.3661x; 1.3661x over previous
//
#include <hip/hip_runtime.h>
#include <cstdint>

#define S_LEN 2048
#define B_SZ 8
#define D_DIM 2048
#define M_DIM (S_LEN * B_SZ)   // 16384 tokens
#define CHAINS (B_SZ * D_DIM)  // 16384 scan chains
#define BK 64
#define KTILES (D_DIM / BK)    // 32

typedef __bf16 bf16;
typedef bf16 bf16x8 __attribute__((ext_vector_type(8)));
typedef bf16 bf16x4 __attribute__((ext_vector_type(4)));
typedef float f32x4 __attribute__((ext_vector_type(4)));

// ---------------- async global->LDS (16B, wave-uniform LDS base + lane*16) ----
__device__ __forceinline__ void async_copy16(void* lds, const void* g) {
    __builtin_amdgcn_global_load_lds(
        (const __attribute__((address_space(1))) unsigned int*)g,
        (__attribute__((address_space(3))) unsigned int*)lds,
        16, 0, 0);
}

// ---------------- fp32 -> bf16 conversion; W interleaved 16-row blocks -------
// wi row layout: rows 32k..32k+15 = Wx channels 16k..16k+15,
//                rows 32k+16..32k+31 = Wa channels 16k..16k+15.
__global__ void k_convert(const float4* __restrict__ x,
                          const float4* __restrict__ wx,
                          const float4* __restrict__ wa,
                          bf16* __restrict__ xb,
                          bf16* __restrict__ wi) {
    const long NX4 = (long)M_DIM * D_DIM / 4;   // 8388608
    const long NW4 = (long)D_DIM * D_DIM / 4;   // 1048576
    const long total = NX4 + 2 * NW4;
    for (long i = (long)blockIdx.x * blockDim.x + threadIdx.x; i < total;
         i += (long)gridDim.x * blockDim.x) {
        float4 v;
        bf16* dst;
        if (i < NX4) {
            v = x[i];
            dst = xb + 4 * i;
        } else {
            long k = i - NX4;
            const int isA = k >= NW4;
            if (isA) k -= NW4;
            const long e = k >> 9;          // source channel row
            const long col4 = k & 511;
            const long drow = (e >> 4) * 32 + (isA ? 16 : 0) + (e & 15);
            v = (isA ? wa : wx)[k];
            dst = wi + (drow * 512 + col4) * 4;
        }
        bf16x4 o;
        o[0] = (bf16)v.x; o[1] = (bf16)v.y; o[2] = (bf16)v.z; o[3] = (bf16)v.w;
        *reinterpret_cast<bf16x4*>(dst) = o;
    }
}

// ---------------- cvec[e] = -C * softplus(a_param[e]) ------------------------
__global__ void k_cvec(const float* __restrict__ ap, float* __restrict__ cv) {
    int e = blockIdx.x * blockDim.x + threadIdx.x;
    if (e < D_DIM) {
        float v = ap[e];
        cv[e] = -8.0f * log1pf(expf(v));
    }
}

// ---------------- single GEMM (interleaved gates) + fused epilogue -----------
// C = xb[16384x2048] @ wi[4096x2048]^T, tile 256x256xBK64, 8 waves (2M x 4N),
// per-wave 128x64 output: acc[8][4]; j even = gate-x, j odd = gate-a for the
// SAME 16 channels/lane mapping -> in-register gate pairing in epilogue.
__global__ __launch_bounds__(512, 2) void k_gemm(
    const bf16* __restrict__ xb,    // [M][D] bf16
    const bf16* __restrict__ wi,    // [2D][D] bf16 interleaved
    const float* __restrict__ x32,  // original x fp32
    const float* __restrict__ bx,
    const float* __restrict__ ba,
    const float* __restrict__ cv,
    float* __restrict__ abuf,       // [M][D] fp32
    float* __restrict__ y)          // [M][D] fp32 (normed_x staged here)
{
    __shared__ __align__(16) char smem[131072];  // 2 x (A 32KB | B 32KB)

    const int tid  = threadIdx.x;
    const int lane = tid & 63;
    const int w    = tid >> 6;       // 8 waves
    const int wm   = w >> 2;         // 0..1 (128 rows each)
    const int wn   = w & 3;          // 0..3 (64 cols each)

    // XCD-bijective swizzle: 1024 wgs = 8 xcds x 128; consecutive same-XCD
    // wgids share the N-panel (B hot in L2).
    const int orig = blockIdx.x;
    const int wgid = (orig & 7) * 128 + (orig >> 3);
    const int m0 = (wgid & 63) * 256;   // 64 M-blocks
    const int e0 = (wgid >> 6) * 256;   // 16 N-blocks (interleaved col space)

    // staging geometry: one instr = 1KB = 8 rows of 128B
    const int srow  = lane >> 3;                 // 0..7
    const int swz16 = ((lane & 7) ^ srow) * 16;  // inverse-swizzled src chunk

    const char* gA = (const char*)xb;
    const char* gB = (const char*)wi;

#define STAGE_A(buf, kt) do {                                                  \
    const long kb_ = (long)(kt) * 128 + swz16;                                 \
    _Pragma("unroll")                                                          \
    for (int j_ = 0; j_ < 4; ++j_) {                                           \
        const int br_ = w * 32 + j_ * 8;                                       \
        async_copy16(smem + (buf) * 65536 + br_ * 128,                         \
                     gA + ((long)(m0 + br_ + srow) * 4096 + kb_));             \
    } } while (0)

#define STAGE_B(buf, kt) do {                                                  \
    const long kb_ = (long)(kt) * 128 + swz16;                                 \
    _Pragma("unroll")                                                          \
    for (int j_ = 0; j_ < 4; ++j_) {                                           \
        const int br_ = w * 32 + j_ * 8;                                       \
        async_copy16(smem + (buf) * 65536 + 32768 + br_ * 128,                 \
                     gB + ((long)(e0 + br_ + srow) * 4096 + kb_));             \
    } } while (0)

#define PHASE_MID() do {                                                       \
    __builtin_amdgcn_s_barrier();                                              \
    asm volatile("s_waitcnt lgkmcnt(0)" ::: "memory");                         \
    __builtin_amdgcn_sched_barrier(0);                                         \
    __builtin_amdgcn_s_setprio(1); } while (0)

#define PHASE_END() do {                                                       \
    __builtin_amdgcn_s_setprio(0);                                             \
    __builtin_amdgcn_s_barrier(); } while (0)

    f32x4 acc[8][4];
#pragma unroll
    for (int i = 0; i < 8; ++i)
#pragma unroll
        for (int j = 0; j < 4; ++j) acc[i][j] = (f32x4)(0.0f);

    // prologue: stage kt=0 into buffer 0, full drain
    STAGE_A(0, 0); STAGE_B(0, 0);
    asm volatile("s_waitcnt vmcnt(0)" ::: "memory");
    __builtin_amdgcn_s_barrier();

    const int rL = lane & 15;

    for (int kt = 0; kt < KTILES; ++kt) {
        const int c  = kt & 1;
        const int nb = 1 - c;
        char* sA = smem + c * 65536;
        char* sB = sA + 32768;
        const bool pf = (kt < KTILES - 1);

        bf16x8 af[4], bf[4];

#define LOAD_AF(ihalf, ks) do {                                                \
    _Pragma("unroll")                                                          \
    for (int i_ = 0; i_ < 4; ++i_) {                                           \
        const int r_ = wm * 128 + ((ihalf) * 4 + i_) * 16 + rL;                \
        const int ch_ = (((ks) * 4 + (lane >> 4)) ^ (r_ & 7)) * 16;            \
        af[i_] = *reinterpret_cast<const bf16x8*>(sA + r_ * 128 + ch_);        \
    } } while (0)

#define LOAD_BF(ks) do {                                                       \
    _Pragma("unroll")                                                          \
    for (int j_ = 0; j_ < 4; ++j_) {                                           \
        const int r_ = wn * 64 + j_ * 16 + rL;                                 \
        const int ch_ = (((ks) * 4 + (lane >> 4)) ^ (r_ & 7)) * 16;            \
        bf[j_] = *reinterpret_cast<const bf16x8*>(sB + r_ * 128 + ch_);        \
    } } while (0)

#define MFMA16(ihalf) do {                                                     \
    _Pragma("unroll")                                                          \
    for (int i_ = 0; i_ < 4; ++i_)                                             \
        _Pragma("unroll")                                                      \
        for (int j_ = 0; j_ < 4; ++j_)                                         \
            acc[(ihalf) * 4 + i_][j_] = __builtin_amdgcn_mfma_f32_16x16x32_bf16( \
                af[i_], bf[j_], acc[(ihalf) * 4 + i_][j_], 0, 0, 0);           \
    } while (0)

        // ---- phase 0: ks=0, ihalf=0 ; stage A(t+1) ----
        LOAD_BF(0); LOAD_AF(0, 0);
        if (pf) STAGE_A(nb, kt + 1);
        PHASE_MID(); MFMA16(0); PHASE_END();

        // ---- phase 1: ks=0, ihalf=1 ; stage B(t+1) ----
        LOAD_AF(1, 0);
        if (pf) STAGE_B(nb, kt + 1);
        PHASE_MID(); MFMA16(1); PHASE_END();

        // ---- phase 2: ks=1, ihalf=0 ----
        LOAD_BF(1); LOAD_AF(0, 1);
        PHASE_MID(); MFMA16(0); PHASE_END();

        // ---- phase 3: ks=1, ihalf=1 ----
        LOAD_AF(1, 1);
        PHASE_MID(); MFMA16(1);
        __builtin_amdgcn_s_setprio(0);
        // boundary: t+1's stages (issued in phases 0/1, ~2.5 phases ago)
        if (pf) asm volatile("s_waitcnt vmcnt(0)" ::: "memory");
        __builtin_amdgcn_s_barrier();

#undef LOAD_AF
#undef LOAD_BF
#undef MFMA16
    }

#undef STAGE_A
#undef STAGE_B
#undef PHASE_MID
#undef PHASE_END

    // ---- epilogue: in-register gate pairing (j even = zx, j odd = za) ----
    const int rgrp = lane >> 4;
    const int chb  = (e0 + wn * 64) >> 1;  // channel base for this wave
#pragma unroll
    for (int jj = 0; jj < 2; ++jj) {
        const int ch = chb + jj * 16 + rL;
        const float bxv = bx[ch];
        const float bav = ba[ch];
        const float cvv = cv[ch];
#pragma unroll
        for (int i = 0; i < 8; ++i) {
#pragma unroll
            for (int r = 0; r < 4; ++r) {
                const int m = m0 + wm * 128 + i * 16 + rgrp * 4 + r;
                const float zx = acc[i][2 * jj][r] + bxv;
                const float za = acc[i][2 * jj + 1][r] + bav;
                const float gx = 1.0f / (1.0f + __expf(-zx));
                const float ga = 1.0f / (1.0f + __expf(-za));
                const float la = cvv * ga;
                float a = __expf(la);
                float mult = sqrtf(fmaxf(1.0f - a * a, 0.0f));
                if (m < B_SZ) { a = 0.0f; mult = 1.0f; }  // s == 0 reset
                const long o = (long)m * D_DIM + ch;
                const float xv = x32[o];
                abuf[o] = a;
                y[o] = xv * gx * mult;
            }
        }
    }
}

// ---------------- in-place scan over S: h = a*h + xn, y <- h -----------------
__global__ __launch_bounds__(64) void k_scan(
    const float* __restrict__ abuf,
    float* __restrict__ y,           // contains xn; overwritten with h states
    const float* __restrict__ h0,
    float* __restrict__ hn) {
    const int c = blockIdx.x * 64 + threadIdx.x;  // chain id, 0..16383
    float h = h0[c];

    float av0[16], xv0[16], av1[16], xv1[16];
    // prologue: load group 0
#pragma unroll
    for (int j = 0; j < 16; ++j) {
        const long o = (long)j * CHAINS + c;
        av0[j] = abuf[o];
        xv0[j] = y[o];
    }
    // 128 groups of 16 steps, ping-pong double-buffer (static indexing only)
    for (int g = 0; g < 128; g += 2) {
        const long base1 = ((long)(g + 1) * 16) * CHAINS + c;
        if (g + 1 < 128) {
#pragma unroll
            for (int j = 0; j < 16; ++j) {
                av1[j] = abuf[base1 + (long)j * CHAINS];
                xv1[j] = y[base1 + (long)j * CHAINS];
            }
        }
        const long base0 = ((long)g * 16) * CHAINS + c;
#pragma unroll
        for (int j = 0; j < 16; ++j) {
            h = fmaf(av0[j], h, xv0[j]);
            y[base0 + (long)j * CHAINS] = h;
        }
        const long base2 = ((long)(g + 2) * 16) * CHAINS + c;
        if (g + 2 < 128) {
#pragma unroll
            for (int j = 0; j < 16; ++j) {
                av0[j] = abuf[base2 + (long)j * CHAINS];
                xv0[j] = y[base2 + (long)j * CHAINS];
            }
        }
        if (g + 1 < 128) {
#pragma unroll
            for (int j = 0; j < 16; ++j) {
                h = fmaf(av1[j], h, xv1[j]);
                y[base1 + (long)j * CHAINS] = h;
            }
        }
    }
    hn[c] = h;
}

// ---------------- launch -----------------------------------------------------
extern "C" void kernel_launch(void* const* d_in, const int* in_sizes, int n_in,
                              void* d_out, int out_size, void* d_ws, size_t ws_size,
                              hipStream_t stream) {
    const float* x  = (const float*)d_in[0];
    const float* h0 = (const float*)d_in[1];
    const float* Wx = (const float*)d_in[2];
    const float* bx = (const float*)d_in[3];
    const float* Wa = (const float*)d_in[4];
    const float* ba = (const float*)d_in[5];
    const float* ap = (const float*)d_in[6];
    float* out = (float*)d_out;

    char* ws = (char*)d_ws;
    // ws layout: xb 0..64MiB | wi 64..80MiB | cv | abuf (128MiB)
    bf16*  xb   = (bf16*)(ws);
    bf16*  wi   = (bf16*)(ws + 67108864L);
    float* cv   = (float*)(ws + 83886080L);
    float* abuf = (float*)(ws + 83894272L);

    float* y  = out;                         // S*B*D
    float* hn = out + (long)M_DIM * D_DIM;   // B*D

    k_convert<<<dim3(2048), dim3(256), 0, stream>>>(
        (const float4*)x, (const float4*)Wx, (const float4*)Wa, xb, wi);
    k_cvec<<<dim3(8), dim3(256), 0, stream>>>(ap, cv);
    k_gemm<<<dim3((M_DIM / 256) * (2 * D_DIM / 256)), dim3(512), 0, stream>>>(
        xb, wi, x, bx, ba, cv, abuf, y);
    k_scan<<<dim3(CHAINS / 64), dim3(64), 0, stream>>>(abuf, y, h0, hn);
}

// Round 6
// 418.136 us; speedup vs baseline: 1.5954x; 1.1679x over previous
//
#include <hip/hip_runtime.h>
#include <cstdint>

#define S_LEN 2048
#define B_SZ 8
#define D_DIM 2048
#define M_DIM (S_LEN * B_SZ)   // 16384 tokens
#define CHAINS (B_SZ * D_DIM)  // 16384 scan chains
#define BK 64
#define KTILES (D_DIM / BK)    // 32

typedef __bf16 bf16;
typedef bf16 bf16x8 __attribute__((ext_vector_type(8)));
typedef bf16 bf16x4 __attribute__((ext_vector_type(4)));
typedef float f32x4 __attribute__((ext_vector_type(4)));

__device__ __forceinline__ void async_copy16(void* lds, const void* g) {
    __builtin_amdgcn_global_load_lds(
        (const __attribute__((address_space(1))) unsigned int*)g,
        (__attribute__((address_space(3))) unsigned int*)lds,
        16, 0, 0);
}

__device__ __forceinline__ unsigned short bf16_bits(float f) {
    bf16 b = (bf16)f;
    return __builtin_bit_cast(unsigned short, b);
}

// ---------------- fp32 -> bf16 conversion; W interleaved 16-row blocks -------
__global__ void k_convert(const float4* __restrict__ x,
                          const float4* __restrict__ wx,
                          const float4* __restrict__ wa,
                          bf16* __restrict__ xb,
                          bf16* __restrict__ wi) {
    const long NX4 = (long)M_DIM * D_DIM / 4;   // 8388608
    const long NW4 = (long)D_DIM * D_DIM / 4;   // 1048576
    const long total = NX4 + 2 * NW4;
    for (long i = (long)blockIdx.x * blockDim.x + threadIdx.x; i < total;
         i += (long)gridDim.x * blockDim.x) {
        float4 v;
        bf16* dst;
        if (i < NX4) {
            v = x[i];
            dst = xb + 4 * i;
        } else {
            long k = i - NX4;
            const int isA = k >= NW4;
            if (isA) k -= NW4;
            const long e = k >> 9;          // source channel row
            const long col4 = k & 511;
            const long drow = (e >> 4) * 32 + (isA ? 16 : 0) + (e & 15);
            v = (isA ? wa : wx)[k];
            dst = wi + (drow * 512 + col4) * 4;
        }
        bf16x4 o;
        o[0] = (bf16)v.x; o[1] = (bf16)v.y; o[2] = (bf16)v.z; o[3] = (bf16)v.w;
        *reinterpret_cast<bf16x4*>(dst) = o;
    }
}

__global__ void k_cvec(const float* __restrict__ ap, float* __restrict__ cv) {
    int e = blockIdx.x * blockDim.x + threadIdx.x;
    if (e < D_DIM) {
        float v = ap[e];
        cv[e] = -8.0f * log1pf(expf(v));
    }
}

// ---------------- single GEMM (interleaved gates), 1-barrier/tile loop -------
// C = xb[16384x2048] @ wi[4096x2048]^T, tile 256x256xBK64, 8 waves (2M x 4N).
// Epilogue packs (bf16 xn | bf16 la) -> u32 pk[M][D].
__global__ __launch_bounds__(512, 2) void k_gemm(
    const bf16* __restrict__ xb,    // [M][D] bf16
    const bf16* __restrict__ wi,    // [2D][D] bf16 interleaved
    const float* __restrict__ bx,
    const float* __restrict__ ba,
    const float* __restrict__ cv,
    unsigned int* __restrict__ pk)  // [M][D] packed (xn<<16 | la)
{
    __shared__ __align__(16) char smem[131072];  // 2 x (A 32KB | B 32KB)

    const int tid  = threadIdx.x;
    const int lane = tid & 63;
    const int w    = tid >> 6;       // 8 waves
    const int wm   = w >> 2;         // 0..1 (128 rows each)
    const int wn   = w & 3;          // 0..3 (64 cols each)

    const int orig = blockIdx.x;
    const int wgid = (orig & 7) * 128 + (orig >> 3);
    const int m0 = (wgid & 63) * 256;   // 64 M-blocks
    const int e0 = (wgid >> 6) * 256;   // 16 N-blocks (interleaved col space)

    const int srow  = lane >> 3;                 // 0..7
    const int swz16 = ((lane & 7) ^ srow) * 16;  // inverse-swizzled src chunk

    const char* gA = (const char*)xb;
    const char* gB = (const char*)wi;

#define STAGE_A(buf, kt) do {                                                  \
    const long kb_ = (long)(kt) * 128 + swz16;                                 \
    _Pragma("unroll")                                                          \
    for (int j_ = 0; j_ < 4; ++j_) {                                           \
        const int br_ = w * 32 + j_ * 8;                                       \
        async_copy16(smem + (buf) * 65536 + br_ * 128,                         \
                     gA + ((long)(m0 + br_ + srow) * 4096 + kb_));             \
    } } while (0)

#define STAGE_B(buf, kt) do {                                                  \
    const long kb_ = (long)(kt) * 128 + swz16;                                 \
    _Pragma("unroll")                                                          \
    for (int j_ = 0; j_ < 4; ++j_) {                                           \
        const int br_ = w * 32 + j_ * 8;                                       \
        async_copy16(smem + (buf) * 65536 + 32768 + br_ * 128,                 \
                     gB + ((long)(e0 + br_ + srow) * 4096 + kb_));             \
    } } while (0)

// phase separator: wait own ds_reads, pin order, boost MFMA wave priority
#define PHASE_GO() do {                                                        \
    asm volatile("s_waitcnt lgkmcnt(0)" ::: "memory");                         \
    __builtin_amdgcn_sched_barrier(0);                                         \
    __builtin_amdgcn_s_setprio(1); } while (0)
#define PHASE_DONE() __builtin_amdgcn_s_setprio(0)

    f32x4 acc[8][4];
#pragma unroll
    for (int i = 0; i < 8; ++i)
#pragma unroll
        for (int j = 0; j < 4; ++j) acc[i][j] = (f32x4)(0.0f);

    // prologue: stage kt=0 into buffer 0
    STAGE_A(0, 0); STAGE_B(0, 0);
    asm volatile("s_waitcnt vmcnt(0)" ::: "memory");
    __builtin_amdgcn_s_barrier();

    const int rL = lane & 15;

    for (int kt = 0; kt < KTILES; ++kt) {
        const int c  = kt & 1;
        const int nb = 1 - c;
        char* sA = smem + c * 65536;
        char* sB = sA + 32768;
        const bool pf = (kt < KTILES - 1);

        bf16x8 af[4], bf[4];

#define LOAD_AF(ihalf, ks) do {                                                \
    _Pragma("unroll")                                                          \
    for (int i_ = 0; i_ < 4; ++i_) {                                           \
        const int r_ = wm * 128 + ((ihalf) * 4 + i_) * 16 + rL;                \
        const int ch_ = (((ks) * 4 + (lane >> 4)) ^ (r_ & 7)) * 16;            \
        af[i_] = *reinterpret_cast<const bf16x8*>(sA + r_ * 128 + ch_);        \
    } } while (0)

#define LOAD_BF(ks) do {                                                       \
    _Pragma("unroll")                                                          \
    for (int j_ = 0; j_ < 4; ++j_) {                                           \
        const int r_ = wn * 64 + j_ * 16 + rL;                                 \
        const int ch_ = (((ks) * 4 + (lane >> 4)) ^ (r_ & 7)) * 16;            \
        bf[j_] = *reinterpret_cast<const bf16x8*>(sB + r_ * 128 + ch_);        \
    } } while (0)

#define MFMA16(ihalf) do {                                                     \
    _Pragma("unroll")                                                          \
    for (int i_ = 0; i_ < 4; ++i_)                                             \
        _Pragma("unroll")                                                      \
        for (int j_ = 0; j_ < 4; ++j_)                                         \
            acc[(ihalf) * 4 + i_][j_] = __builtin_amdgcn_mfma_f32_16x16x32_bf16( \
                af[i_], bf[j_], acc[(ihalf) * 4 + i_][j_], 0, 0, 0);           \
    } while (0)

        // phase 0: ks=0 ihalf=0 ; stage A(t+1)
        LOAD_BF(0); LOAD_AF(0, 0);
        if (pf) STAGE_A(nb, kt + 1);
        PHASE_GO(); MFMA16(0); PHASE_DONE();

        // phase 1: ks=0 ihalf=1 ; stage B(t+1)
        LOAD_AF(1, 0);
        if (pf) STAGE_B(nb, kt + 1);
        PHASE_GO(); MFMA16(1); PHASE_DONE();

        // phase 2: ks=1 ihalf=0
        LOAD_BF(1); LOAD_AF(0, 1);
        PHASE_GO(); MFMA16(0); PHASE_DONE();

        // phase 3: ks=1 ihalf=1
        LOAD_AF(1, 1);
        PHASE_GO(); MFMA16(1); PHASE_DONE();

        // single tile-boundary sync: own stages landed (issued 3-4 phases ago),
        // then block barrier releases buffer c and publishes buffer nb.
        if (pf) asm volatile("s_waitcnt vmcnt(0)" ::: "memory");
        __builtin_amdgcn_s_barrier();

#undef LOAD_AF
#undef LOAD_BF
#undef MFMA16
    }

#undef STAGE_A
#undef STAGE_B
#undef PHASE_GO
#undef PHASE_DONE

    // ---- epilogue: gates in-register, pack (bf16 xn | bf16 la) ----
    const int rgrp = lane >> 4;
    const int chb  = (e0 + wn * 64) >> 1;  // real channel base for this wave
#pragma unroll
    for (int jj = 0; jj < 2; ++jj) {
        const int ch = chb + jj * 16 + rL;
        const float bxv = bx[ch];
        const float bav = ba[ch];
        const float cvv = cv[ch];
#pragma unroll
        for (int i = 0; i < 8; ++i) {
#pragma unroll
            for (int r = 0; r < 4; ++r) {
                const int m = m0 + wm * 128 + i * 16 + rgrp * 4 + r;
                const float zx = acc[i][2 * jj][r] + bxv;
                const float za = acc[i][2 * jj + 1][r] + bav;
                const float gx = 1.0f / (1.0f + __expf(-zx));
                const float ga = 1.0f / (1.0f + __expf(-za));
                float la = cvv * ga;
                float mult = sqrtf(fmaxf(1.0f - __expf(2.0f * la), 0.0f));
                if (m < B_SZ) { la = -100.0f; mult = 1.0f; }  // s==0 reset
                const long o = (long)m * D_DIM + ch;
                const float xv = (float)xb[o];
                const float xn = xv * gx * mult;
                const unsigned int u =
                    ((unsigned int)bf16_bits(xn) << 16) | bf16_bits(la);
                pk[o] = u;
            }
        }
    }
}

// ---------------- scan: h = exp(la)*h + xn over S, y <- h --------------------
__global__ __launch_bounds__(64) void k_scan(
    const unsigned int* __restrict__ pk,
    float* __restrict__ y,
    const float* __restrict__ h0,
    float* __restrict__ hn) {
    const int c = blockIdx.x * 64 + threadIdx.x;  // chain id
    float h = h0[c];

    unsigned int u0[16], u1[16];
#pragma unroll
    for (int j = 0; j < 16; ++j) u0[j] = pk[(long)j * CHAINS + c];

    for (int g = 0; g < 128; g += 2) {
        const long base1 = ((long)(g + 1) * 16) * CHAINS + c;
        if (g + 1 < 128) {
#pragma unroll
            for (int j = 0; j < 16; ++j) u1[j] = pk[base1 + (long)j * CHAINS];
        }
        const long base0 = ((long)g * 16) * CHAINS + c;
#pragma unroll
        for (int j = 0; j < 16; ++j) {
            const unsigned int u = u0[j];
            const float la = __builtin_bit_cast(float, u << 16);
            const float xn = __builtin_bit_cast(float, u & 0xffff0000u);
            h = fmaf(__expf(la), h, xn);
            y[base0 + (long)j * CHAINS] = h;
        }
        const long base2 = ((long)(g + 2) * 16) * CHAINS + c;
        if (g + 2 < 128) {
#pragma unroll
            for (int j = 0; j < 16; ++j) u0[j] = pk[base2 + (long)j * CHAINS];
        }
        if (g + 1 < 128) {
#pragma unroll
            for (int j = 0; j < 16; ++j) {
                const unsigned int u = u1[j];
                const float la = __builtin_bit_cast(float, u << 16);
                const float xn = __builtin_bit_cast(float, u & 0xffff0000u);
                h = fmaf(__expf(la), h, xn);
                y[base1 + (long)j * CHAINS] = h;
            }
        }
    }
    hn[c] = h;
}

// ---------------- launch -----------------------------------------------------
extern "C" void kernel_launch(void* const* d_in, const int* in_sizes, int n_in,
                              void* d_out, int out_size, void* d_ws, size_t ws_size,
                              hipStream_t stream) {
    const float* x  = (const float*)d_in[0];
    const float* h0 = (const float*)d_in[1];
    const float* Wx = (const float*)d_in[2];
    const float* bx = (const float*)d_in[3];
    const float* Wa = (const float*)d_in[4];
    const float* ba = (const float*)d_in[5];
    const float* ap = (const float*)d_in[6];
    float* out = (float*)d_out;

    char* ws = (char*)d_ws;
    // ws: xb 0..64MiB | wi 64..80MiB | cv @80MiB | pk @80MiB+8KiB (128MiB)
    bf16*  xb = (bf16*)(ws);
    bf16*  wi = (bf16*)(ws + 67108864L);
    float* cv = (float*)(ws + 83886080L);
    unsigned int* pk = (unsigned int*)(ws + 83894272L);

    float* y  = out;                         // S*B*D
    float* hn = out + (long)M_DIM * D_DIM;   // B*D

    k_convert<<<dim3(2048), dim3(256), 0, stream>>>(
        (const float4*)x, (const float4*)Wx, (const float4*)Wa, xb, wi);
    k_cvec<<<dim3(8), dim3(256), 0, stream>>>(ap, cv);
    k_gemm<<<dim3((M_DIM / 256) * (2 * D_DIM / 256)), dim3(512), 0, stream>>>(
        xb, wi, bx, ba, cv, pk);
    k_scan<<<dim3(CHAINS / 64), dim3(64), 0, stream>>>(pk, y, h0, hn);
}